// Round 5
// baseline (205.101 us; speedup 1.0000x reference)
//
#include <hip/hip_runtime.h>
#include <math.h>

#define D 128

// ---------------------------------------------------------------------------
// Kernel 1: per-node attention logit  s[n] = dot(W2, tanh(W1 @ N[n]))
// Lane = node. Each lane holds its N row in 128 VGPRs (32 float4).
// W1[e][*] / W2[e] are wave-uniform -> scalar loads through the constant
// cache (no LDS, no VALU cost for operand fetch). The 128 e-rows are split
// across the block's 4 waves (32 each) -> 782 blocks, ~3 blocks/CU.
// 4 independent FMA accumulator chains hide fp32 FMA latency.
// ---------------------------------------------------------------------------
__global__ __launch_bounds__(256, 3) void node_score_kernel(
    const float* __restrict__ Nmat, const float* __restrict__ W1,
    const float* __restrict__ W2, float* __restrict__ s, int nNodes)
{
    __shared__ float partial[4][64];
    const int t = threadIdx.x;
    const int lane = t & 63;
    // readfirstlane so the compiler proves e-addresses uniform -> s_load
    const int wv = __builtin_amdgcn_readfirstlane(t >> 6);
    const int base = blockIdx.x * 64;
    const int node = base + lane;
    const bool valid = node < nNodes;

    const float4* N4 = (const float4*)Nmat;
    float4 nv[32];
    #pragma unroll
    for (int c = 0; c < 32; ++c) {
        nv[c] = valid ? N4[(size_t)node * 32 + c] : make_float4(0.f, 0.f, 0.f, 0.f);
    }

    const int e0 = wv * 32;
    float sacc = 0.f;
    #pragma unroll 2
    for (int ee = 0; ee < 32; ++ee) {
        const int e = e0 + ee;
        const float4* __restrict__ w1r = (const float4*)(W1 + e * D);
        float a0 = 0.f, a1 = 0.f, a2 = 0.f, a3 = 0.f;
        #pragma unroll
        for (int c = 0; c < 32; ++c) {
            float4 w = w1r[c];          // uniform -> s_load_dwordx16
            a0 = fmaf(w.x, nv[c].x, a0);
            a1 = fmaf(w.y, nv[c].y, a1);
            a2 = fmaf(w.z, nv[c].z, a2);
            a3 = fmaf(w.w, nv[c].w, a3);
        }
        float h = (a0 + a1) + (a2 + a3);
        sacc = fmaf(W2[e], tanhf(h), sacc);
    }

    partial[wv][lane] = sacc;
    __syncthreads();
    if (t < 64) {
        float v = partial[0][t] + partial[1][t] + partial[2][t] + partial[3][t];
        int n = base + t;
        if (n < nNodes) s[n] = v;
    }
}

// ---------------------------------------------------------------------------
// Kernel 2: CSR offsets from sorted dst.  off[v] = first edge with dst >= v,
// off[nNodes] = nEdges.  Every entry written exactly once (no init needed).
// ---------------------------------------------------------------------------
__global__ void build_off_kernel(const int* __restrict__ dst, int* __restrict__ off,
                                 int nEdges, int nNodes)
{
    int i = blockIdx.x * blockDim.x + threadIdx.x;
    if (i >= nEdges) return;
    int d = dst[i];
    int dprev = (i == 0) ? -1 : dst[i - 1];
    for (int v = dprev + 1; v <= d; ++v) off[v] = i;
    if (i == nEdges - 1) {
        for (int v = d + 1; v <= nNodes; ++v) off[v] = nEdges;
    }
}

// ---------------------------------------------------------------------------
// Kernel 3: per-destination segment softmax + weighted neighbor sum.
// One 64-lane wave per destination node; lane l owns output columns 2l, 2l+1.
// ---------------------------------------------------------------------------
__global__ __launch_bounds__(256) void aggregate_kernel(
    const float* __restrict__ Nmat, const int* __restrict__ src,
    const float* __restrict__ s, const int* __restrict__ off,
    float* __restrict__ out, int nNodes)
{
    const int wave = threadIdx.x >> 6, lane = threadIdx.x & 63;
    const int v = blockIdx.x * 4 + wave;
    if (v >= nNodes) return;

    const int start = off[v], end = off[v + 1];
    const int deg = end - start;

    float2 acc = make_float2(0.f, 0.f);

    if (deg > 0) {
        // ---- phase 1: per-lane edge score, wave max ----
        float e_val = -INFINITY;
        int src_val = 0;
        if (lane < deg) {
            src_val = src[start + lane];
            e_val = s[src_val];
        }
        float m = e_val;
        for (int i = start + 64 + lane; i < end; i += 64)
            m = fmaxf(m, s[src[i]]);
        #pragma unroll
        for (int o = 32; o > 0; o >>= 1) m = fmaxf(m, __shfl_xor(m, o, 64));

        // ---- phase 2: sum of exp ----
        float w_val = (lane < deg) ? expf(e_val - m) : 0.f;
        float z = w_val;
        for (int i = start + 64 + lane; i < end; i += 64)
            z += expf(s[src[i]] - m);
        #pragma unroll
        for (int o = 32; o > 0; o >>= 1) z += __shfl_xor(z, o, 64);
        const float invz = 1.0f / z;

        // ---- phase 3: weighted row accumulation ----
        const float2* N2 = (const float2*)Nmat;
        const int dmain = min(deg, 64);
        for (int j = 0; j < dmain; ++j) {
            float wj = __shfl(w_val, j, 64) * invz;
            int sj = __shfl(src_val, j, 64);
            float2 nvv = N2[(size_t)sj * 64 + lane];
            acc.x = fmaf(wj, nvv.x, acc.x);
            acc.y = fmaf(wj, nvv.y, acc.y);
        }
        // rare fallback: degree > 64
        for (int i = start + 64; i < end; ++i) {
            int sj = src[i];                       // uniform across lanes
            float wj = expf(s[sj] - m) * invz;
            float2 nvv = N2[(size_t)sj * 64 + lane];
            acc.x = fmaf(wj, nvv.x, acc.x);
            acc.y = fmaf(wj, nvv.y, acc.y);
        }
    }
    ((float2*)out)[(size_t)v * 64 + lane] = acc;   // zeros for deg==0 nodes
}

// ---------------------------------------------------------------------------
extern "C" void kernel_launch(void* const* d_in, const int* in_sizes, int n_in,
                              void* d_out, int out_size, void* d_ws, size_t ws_size,
                              hipStream_t stream)
{
    const float* Nmat = (const float*)d_in[0];
    const int* src    = (const int*)d_in[1];
    const int* dst    = (const int*)d_in[2];
    const float* W1   = (const float*)d_in[3];
    const float* W2   = (const float*)d_in[4];
    float* out        = (float*)d_out;

    const int nNodes = in_sizes[0] / D;
    const int nEdges = in_sizes[1];

    // workspace layout: s [nNodes floats] | off [nNodes+1 ints]
    float* s  = (float*)d_ws;
    int* off  = (int*)((char*)d_ws + ((((size_t)nNodes * 4) + 255) & ~(size_t)255));

    node_score_kernel<<<(nNodes + 63) / 64, 256, 0, stream>>>(Nmat, W1, W2, s, nNodes);
    build_off_kernel<<<(nEdges + 255) / 256, 256, 0, stream>>>(dst, off, nEdges, nNodes);
    aggregate_kernel<<<(nNodes + 3) / 4, 256, 0, stream>>>(Nmat, src, s, off, out, nNodes);
}

// Round 6
// 149.017 us; speedup vs baseline: 1.3764x; 1.3764x over previous
//
#include <hip/hip_runtime.h>
#include <math.h>

#define D 128

typedef __attribute__((ext_vector_type(8))) short short8;
typedef __attribute__((ext_vector_type(4))) float floatx4;
typedef __attribute__((ext_vector_type(4))) unsigned short ushortx4;

__device__ __forceinline__ unsigned short f2bf(float f) {
    union { float f; unsigned u; } v; v.f = f;
    unsigned u = v.u;
    u += 0x7FFFu + ((u >> 16) & 1u);      // round-to-nearest-even
    return (unsigned short)(u >> 16);
}

// ---------------------------------------------------------------------------
// Kernel 1: per-node attention logit  s[n] = dot(W2, tanh(W1 @ N[n]))
// bf16 MFMA version. Per block: 64 nodes. W1 (bf16, padded [128][136]) and
// the N-tile (bf16, [64][136]) staged in LDS; pad makes row stride 272 B =
// 4-bank rotation -> balanced ds_read_b128. 4 waves x 8 e-tiles x 4 k-steps
// of mfma_f32_16x16x32_bf16 (fp32 accumulate), then tanh/W2 epilogue with a
// 16-lane shfl_xor reduction. LDS 52.7 KB -> 3 blocks/CU.
// ---------------------------------------------------------------------------
__global__ __launch_bounds__(256) void node_score_kernel(
    const float* __restrict__ Nmat, const float* __restrict__ W1,
    const float* __restrict__ W2, float* __restrict__ s, int nNodes)
{
    __shared__ __attribute__((aligned(16))) unsigned short W1s[128][136];
    __shared__ __attribute__((aligned(16))) unsigned short Ns[64][136];
    __shared__ float W2s[128];

    const int t = threadIdx.x;
    const int base = blockIdx.x * 64;
    const float4* W14 = (const float4*)W1;
    const float4* N4  = (const float4*)Nmat;

    // stage W1 -> bf16 LDS (4096 float4s, 16 per thread, coalesced)
    #pragma unroll
    for (int k = 0; k < 16; ++k) {
        int idx = t + k * 256;
        int row = idx >> 5, c4 = idx & 31;
        float4 wv = W14[idx];
        ushortx4 p;
        p.x = f2bf(wv.x); p.y = f2bf(wv.y); p.z = f2bf(wv.z); p.w = f2bf(wv.w);
        *(ushortx4*)&W1s[row][c4 * 4] = p;
    }
    // stage N tile -> bf16 LDS (2048 float4s, 8 per thread)
    #pragma unroll
    for (int k = 0; k < 8; ++k) {
        int idx = t + k * 256;
        int n = idx >> 5, c4 = idx & 31;
        int gn = base + n;
        float4 nv = (gn < nNodes) ? N4[(size_t)gn * 32 + c4]
                                  : make_float4(0.f, 0.f, 0.f, 0.f);
        ushortx4 p;
        p.x = f2bf(nv.x); p.y = f2bf(nv.y); p.z = f2bf(nv.z); p.w = f2bf(nv.w);
        *(ushortx4*)&Ns[n][c4 * 4] = p;
    }
    if (t < 128) W2s[t] = W2[t];
    __syncthreads();

    const int w = t >> 6, l = t & 63;
    const int lr = l & 15, lg = l >> 4;

    floatx4 acc[8];
    #pragma unroll
    for (int et = 0; et < 8; ++et) acc[et] = (floatx4){0.f, 0.f, 0.f, 0.f};

    // H[16 nodes][128 e] per wave: A row = node (lane&15), B col = e (lane&15),
    // both frags read contiguous 8 bf16 at k-offset (lane>>4)*8.
    #pragma unroll
    for (int kk = 0; kk < 4; ++kk) {
        short8 a = *(const short8*)&Ns[w * 16 + lr][kk * 32 + lg * 8];
        #pragma unroll
        for (int et = 0; et < 8; ++et) {
            short8 b = *(const short8*)&W1s[et * 16 + lr][kk * 32 + lg * 8];
            acc[et] = __builtin_amdgcn_mfma_f32_16x16x32_bf16(a, b, acc[et], 0, 0, 0);
        }
    }

    // epilogue: s[node] = sum_e W2[e] * tanh(H[node][e])
    // C/D layout: col(e) = lane&15, row(node) = (lane>>4)*4 + reg  [m89]
    float sacc[4] = {0.f, 0.f, 0.f, 0.f};
    #pragma unroll
    for (int et = 0; et < 8; ++et) {
        float w2v = W2s[et * 16 + lr];
        #pragma unroll
        for (int r = 0; r < 4; ++r)
            sacc[r] = fmaf(w2v, tanhf(acc[et][r]), sacc[r]);
    }
    #pragma unroll
    for (int r = 0; r < 4; ++r) {
        float v = sacc[r];
        v += __shfl_xor(v, 1, 64);
        v += __shfl_xor(v, 2, 64);
        v += __shfl_xor(v, 4, 64);
        v += __shfl_xor(v, 8, 64);
        int node = base + w * 16 + lg * 4 + r;
        if (lr == 0 && node < nNodes) s[node] = v;
    }
}

// ---------------------------------------------------------------------------
// Kernel 2: CSR offsets from sorted dst.  off[v] = first edge with dst >= v,
// off[nNodes] = nEdges.  Every entry written exactly once (no init needed).
// ---------------------------------------------------------------------------
__global__ void build_off_kernel(const int* __restrict__ dst, int* __restrict__ off,
                                 int nEdges, int nNodes)
{
    int i = blockIdx.x * blockDim.x + threadIdx.x;
    if (i >= nEdges) return;
    int d = dst[i];
    int dprev = (i == 0) ? -1 : dst[i - 1];
    for (int v = dprev + 1; v <= d; ++v) off[v] = i;
    if (i == nEdges - 1) {
        for (int v = d + 1; v <= nNodes; ++v) off[v] = nEdges;
    }
}

// ---------------------------------------------------------------------------
// Kernel 3: per-destination segment softmax + weighted neighbor sum.
// One 64-lane wave per destination node; lane l owns output columns 2l, 2l+1.
// ---------------------------------------------------------------------------
__global__ __launch_bounds__(256) void aggregate_kernel(
    const float* __restrict__ Nmat, const int* __restrict__ src,
    const float* __restrict__ s, const int* __restrict__ off,
    float* __restrict__ out, int nNodes)
{
    const int wave = threadIdx.x >> 6, lane = threadIdx.x & 63;
    const int v = blockIdx.x * 4 + wave;
    if (v >= nNodes) return;

    const int start = off[v], end = off[v + 1];
    const int deg = end - start;

    float2 acc = make_float2(0.f, 0.f);

    if (deg > 0) {
        // ---- phase 1: per-lane edge score, wave max ----
        float e_val = -INFINITY;
        int src_val = 0;
        if (lane < deg) {
            src_val = src[start + lane];
            e_val = s[src_val];
        }
        float m = e_val;
        for (int i = start + 64 + lane; i < end; i += 64)
            m = fmaxf(m, s[src[i]]);
        #pragma unroll
        for (int o = 32; o > 0; o >>= 1) m = fmaxf(m, __shfl_xor(m, o, 64));

        // ---- phase 2: sum of exp ----
        float w_val = (lane < deg) ? expf(e_val - m) : 0.f;
        float z = w_val;
        for (int i = start + 64 + lane; i < end; i += 64)
            z += expf(s[src[i]] - m);
        #pragma unroll
        for (int o = 32; o > 0; o >>= 1) z += __shfl_xor(z, o, 64);
        const float invz = 1.0f / z;

        // ---- phase 3: weighted row accumulation ----
        const float2* N2 = (const float2*)Nmat;
        const int dmain = min(deg, 64);
        for (int j = 0; j < dmain; ++j) {
            float wj = __shfl(w_val, j, 64) * invz;
            int sj = __shfl(src_val, j, 64);
            float2 nvv = N2[(size_t)sj * 64 + lane];
            acc.x = fmaf(wj, nvv.x, acc.x);
            acc.y = fmaf(wj, nvv.y, acc.y);
        }
        // rare fallback: degree > 64
        for (int i = start + 64; i < end; ++i) {
            int sj = src[i];                       // uniform across lanes
            float wj = expf(s[sj] - m) * invz;
            float2 nvv = N2[(size_t)sj * 64 + lane];
            acc.x = fmaf(wj, nvv.x, acc.x);
            acc.y = fmaf(wj, nvv.y, acc.y);
        }
    }
    ((float2*)out)[(size_t)v * 64 + lane] = acc;   // zeros for deg==0 nodes
}

// ---------------------------------------------------------------------------
extern "C" void kernel_launch(void* const* d_in, const int* in_sizes, int n_in,
                              void* d_out, int out_size, void* d_ws, size_t ws_size,
                              hipStream_t stream)
{
    const float* Nmat = (const float*)d_in[0];
    const int* src    = (const int*)d_in[1];
    const int* dst    = (const int*)d_in[2];
    const float* W1   = (const float*)d_in[3];
    const float* W2   = (const float*)d_in[4];
    float* out        = (float*)d_out;

    const int nNodes = in_sizes[0] / D;
    const int nEdges = in_sizes[1];

    // workspace layout: s [nNodes floats] | off [nNodes+1 ints]
    float* s  = (float*)d_ws;
    int* off  = (int*)((char*)d_ws + ((((size_t)nNodes * 4) + 255) & ~(size_t)255));

    node_score_kernel<<<(nNodes + 63) / 64, 256, 0, stream>>>(Nmat, W1, W2, s, nNodes);
    build_off_kernel<<<(nEdges + 255) / 256, 256, 0, stream>>>(dst, off, nEdges, nNodes);
    aggregate_kernel<<<(nNodes + 3) / 4, 256, 0, stream>>>(Nmat, src, s, off, out, nNodes);
}

// Round 14
// 145.823 us; speedup vs baseline: 1.4065x; 1.0219x over previous
//
#include <hip/hip_runtime.h>
#include <math.h>

#define D 128

typedef __attribute__((ext_vector_type(8))) short short8;
typedef __attribute__((ext_vector_type(4))) float floatx4;
typedef __attribute__((ext_vector_type(4))) unsigned short ushortx4;
typedef __attribute__((ext_vector_type(8))) unsigned short ushortx8;

__device__ __forceinline__ unsigned short f2bf(float f) {
    union { float f; unsigned u; } v; v.f = f;
    unsigned u = v.u;
    u += 0x7FFFu + ((u >> 16) & 1u);      // round-to-nearest-even
    return (unsigned short)(u >> 16);
}

__device__ __forceinline__ float bflo(unsigned u) {
    union { unsigned u; float f; } v; v.u = u << 16; return v.f;
}
__device__ __forceinline__ float bfhi(unsigned u) {
    union { unsigned u; float f; } v; v.u = u & 0xFFFF0000u; return v.f;
}

// ---------------------------------------------------------------------------
// Kernel 1: per-node attention logit  s[n] = dot(W2, tanh(W1 @ N[n]))
// bf16 MFMA version (measured: 149us total round 6). Per block: 64 nodes.
// W1 (bf16 [128][136] pad) + N-tile (bf16 [64][136]) in LDS; 4 waves x
// 8 e-tiles x 4 k-steps of mfma_f32_16x16x32_bf16; tanh/W2 epilogue with
// 16-lane shfl_xor reduce. Also streams the bf16 N-tile to global Nbf
// (FULL 256 B/row: 16 ushortx8 chunks per row — round-8 bug was 8).
// ---------------------------------------------------------------------------
__global__ __launch_bounds__(256) void node_score_kernel(
    const float* __restrict__ Nmat, const float* __restrict__ W1,
    const float* __restrict__ W2, float* __restrict__ s,
    ushortx8* __restrict__ nbf, int nNodes)
{
    __shared__ __attribute__((aligned(16))) unsigned short W1s[128][136];
    __shared__ __attribute__((aligned(16))) unsigned short Ns[64][136];
    __shared__ float W2s[128];

    const int t = threadIdx.x;
    const int base = blockIdx.x * 64;
    const float4* W14 = (const float4*)W1;
    const float4* N4  = (const float4*)Nmat;

    // stage W1 -> bf16 LDS (4096 float4s, 16 per thread, coalesced)
    #pragma unroll
    for (int k = 0; k < 16; ++k) {
        int idx = t + k * 256;
        int row = idx >> 5, c4 = idx & 31;
        float4 wv = W14[idx];
        ushortx4 p;
        p.x = f2bf(wv.x); p.y = f2bf(wv.y); p.z = f2bf(wv.z); p.w = f2bf(wv.w);
        *(ushortx4*)&W1s[row][c4 * 4] = p;
    }
    // stage N tile -> bf16 LDS (2048 float4s, 8 per thread)
    #pragma unroll
    for (int k = 0; k < 8; ++k) {
        int idx = t + k * 256;
        int n = idx >> 5, c4 = idx & 31;
        int gn = base + n;
        float4 nv = (gn < nNodes) ? N4[(size_t)gn * 32 + c4]
                                  : make_float4(0.f, 0.f, 0.f, 0.f);
        ushortx4 p;
        p.x = f2bf(nv.x); p.y = f2bf(nv.y); p.z = f2bf(nv.z); p.w = f2bf(nv.w);
        *(ushortx4*)&Ns[n][c4 * 4] = p;
    }
    if (t < 128) W2s[t] = W2[t];
    __syncthreads();

    // stream bf16 N tile to workspace: 64 rows x 16 ushortx8 chunks = 1024
    // chunks (256 B/row). Row stride = 16 chunks; matches aggregate's
    // Nbf[sj*64 + lane] uint reads (sj*256 + lane*4 bytes).
    if (nbf) {
        #pragma unroll
        for (int k = 0; k < 4; ++k) {
            int idx = t + k * 256;            // 0..1023
            int n = idx >> 4, c8 = idx & 15;
            int gn = base + n;
            if (gn < nNodes)
                nbf[(size_t)gn * 16 + c8] = *(const ushortx8*)&Ns[n][c8 * 8];
        }
    }

    const int w = t >> 6, l = t & 63;
    const int lr = l & 15, lg = l >> 4;

    floatx4 acc[8];
    #pragma unroll
    for (int et = 0; et < 8; ++et) acc[et] = (floatx4){0.f, 0.f, 0.f, 0.f};

    // H[16 nodes][128 e] per wave: A row = node (lane&15), B col = e (lane&15),
    // both frags read contiguous 8 bf16 at k-offset (lane>>4)*8.
    #pragma unroll
    for (int kk = 0; kk < 4; ++kk) {
        short8 a = *(const short8*)&Ns[w * 16 + lr][kk * 32 + lg * 8];
        #pragma unroll
        for (int et = 0; et < 8; ++et) {
            short8 b = *(const short8*)&W1s[et * 16 + lr][kk * 32 + lg * 8];
            acc[et] = __builtin_amdgcn_mfma_f32_16x16x32_bf16(a, b, acc[et], 0, 0, 0);
        }
    }

    // epilogue: s[node] = sum_e W2[e] * tanh(H[node][e])
    // C/D layout: col(e) = lane&15, row(node) = (lane>>4)*4 + reg  [m89]
    float sacc[4] = {0.f, 0.f, 0.f, 0.f};
    #pragma unroll
    for (int et = 0; et < 8; ++et) {
        float w2v = W2s[et * 16 + lr];
        #pragma unroll
        for (int r = 0; r < 4; ++r)
            sacc[r] = fmaf(w2v, tanhf(acc[et][r]), sacc[r]);
    }
    #pragma unroll
    for (int r = 0; r < 4; ++r) {
        float v = sacc[r];
        v += __shfl_xor(v, 1, 64);
        v += __shfl_xor(v, 2, 64);
        v += __shfl_xor(v, 4, 64);
        v += __shfl_xor(v, 8, 64);
        int node = base + w * 16 + lg * 4 + r;
        if (lr == 0 && node < nNodes) s[node] = v;
    }
}

// ---------------------------------------------------------------------------
// Kernel 2: CSR offsets from sorted dst.  off[v] = first edge with dst >= v,
// off[nNodes] = nEdges.  Every entry written exactly once (no init needed).
// ---------------------------------------------------------------------------
__global__ void build_off_kernel(const int* __restrict__ dst, int* __restrict__ off,
                                 int nEdges, int nNodes)
{
    int i = blockIdx.x * blockDim.x + threadIdx.x;
    if (i >= nEdges) return;
    int d = dst[i];
    int dprev = (i == 0) ? -1 : dst[i - 1];
    for (int v = dprev + 1; v <= d; ++v) off[v] = i;
    if (i == nEdges - 1) {
        for (int v = d + 1; v <= nNodes; ++v) off[v] = nEdges;
    }
}

// ---------------------------------------------------------------------------
// Kernel 3: per-destination segment softmax + weighted neighbor sum.
// One 64-lane wave per destination node.
// BF=1: gather bf16 rows from workspace copy (4 B/lane, 256 B/row — halves
// the L2-miss gather traffic).  BF=0: fp32 fallback (8 B/lane).
// ---------------------------------------------------------------------------
template <int BF>
__global__ __launch_bounds__(256) void aggregate_kernel(
    const float* __restrict__ Nmat, const unsigned* __restrict__ Nbf,
    const int* __restrict__ src, const float* __restrict__ s,
    const int* __restrict__ off, float* __restrict__ out, int nNodes)
{
    const int wave = threadIdx.x >> 6, lane = threadIdx.x & 63;
    const int v = blockIdx.x * 4 + wave;
    if (v >= nNodes) return;

    const int start = off[v], end = off[v + 1];
    const int deg = end - start;

    float2 acc = make_float2(0.f, 0.f);

    if (deg > 0) {
        // ---- phase 1: per-lane edge score, wave max ----
        float e_val = -INFINITY;
        int src_val = 0;
        if (lane < deg) {
            src_val = src[start + lane];
            e_val = s[src_val];
        }
        float m = e_val;
        for (int i = start + 64 + lane; i < end; i += 64)
            m = fmaxf(m, s[src[i]]);
        #pragma unroll
        for (int o = 32; o > 0; o >>= 1) m = fmaxf(m, __shfl_xor(m, o, 64));

        // ---- phase 2: sum of exp ----
        float w_val = (lane < deg) ? expf(e_val - m) : 0.f;
        float z = w_val;
        for (int i = start + 64 + lane; i < end; i += 64)
            z += expf(s[src[i]] - m);
        #pragma unroll
        for (int o = 32; o > 0; o >>= 1) z += __shfl_xor(z, o, 64);
        const float invz = 1.0f / z;

        // ---- phase 3: weighted row accumulation ----
        const float2* N2 = (const float2*)Nmat;
        const int dmain = min(deg, 64);
        for (int j = 0; j < dmain; ++j) {
            float wj = __shfl(w_val, j, 64) * invz;
            int sj = __shfl(src_val, j, 64);
            if (BF) {
                unsigned u = Nbf[(size_t)sj * 64 + lane];
                acc.x = fmaf(wj, bflo(u), acc.x);
                acc.y = fmaf(wj, bfhi(u), acc.y);
            } else {
                float2 nvv = N2[(size_t)sj * 64 + lane];
                acc.x = fmaf(wj, nvv.x, acc.x);
                acc.y = fmaf(wj, nvv.y, acc.y);
            }
        }
        // rare fallback: degree > 64
        for (int i = start + 64; i < end; ++i) {
            int sj = src[i];                       // uniform across lanes
            float wj = expf(s[sj] - m) * invz;
            if (BF) {
                unsigned u = Nbf[(size_t)sj * 64 + lane];
                acc.x = fmaf(wj, bflo(u), acc.x);
                acc.y = fmaf(wj, bfhi(u), acc.y);
            } else {
                float2 nvv = N2[(size_t)sj * 64 + lane];
                acc.x = fmaf(wj, nvv.x, acc.x);
                acc.y = fmaf(wj, nvv.y, acc.y);
            }
        }
    }
    ((float2*)out)[(size_t)v * 64 + lane] = acc;   // zeros for deg==0 nodes
}

// ---------------------------------------------------------------------------
extern "C" void kernel_launch(void* const* d_in, const int* in_sizes, int n_in,
                              void* d_out, int out_size, void* d_ws, size_t ws_size,
                              hipStream_t stream)
{
    const float* Nmat = (const float*)d_in[0];
    const int* src    = (const int*)d_in[1];
    const int* dst    = (const int*)d_in[2];
    const float* W1   = (const float*)d_in[3];
    const float* W2   = (const float*)d_in[4];
    float* out        = (float*)d_out;

    const int nNodes = in_sizes[0] / D;
    const int nEdges = in_sizes[1];

    // workspace layout: s [nNodes f32] | off [nNodes+1 i32] | Nbf [nNodes*128 bf16]
    size_t o_s   = 0;
    size_t o_off = (o_s + (size_t)nNodes * 4 + 255) & ~(size_t)255;
    size_t o_nbf = (o_off + ((size_t)nNodes + 1) * 4 + 255) & ~(size_t)255;
    size_t need  = o_nbf + (size_t)nNodes * D * 2;

    float* s  = (float*)((char*)d_ws + o_s);
    int* off  = (int*)((char*)d_ws + o_off);
    const bool use_bf = (ws_size >= need);
    ushortx8* nbf = use_bf ? (ushortx8*)((char*)d_ws + o_nbf) : nullptr;

    node_score_kernel<<<(nNodes + 63) / 64, 256, 0, stream>>>(Nmat, W1, W2, s, nbf, nNodes);
    build_off_kernel<<<(nEdges + 255) / 256, 256, 0, stream>>>(dst, off, nEdges, nNodes);
    if (use_bf)
        aggregate_kernel<1><<<(nNodes + 3) / 4, 256, 0, stream>>>(
            Nmat, (const unsigned*)nbf, src, s, off, out, nNodes);
    else
        aggregate_kernel<0><<<(nNodes + 3) / 4, 256, 0, stream>>>(
            Nmat, nullptr, src, s, off, out, nNodes);
}